// Round 7
// baseline (39.609 us; speedup 1.0000x reference)
//
#include <hip/hip_runtime.h>
#include <math.h>

#define ALPHA 0.2f
#define MAXK 10

typedef _Float16 half8 __attribute__((ext_vector_type(8)));
typedef _Float16 half4 __attribute__((ext_vector_type(4)));
typedef float f32x4 __attribute__((ext_vector_type(4)));

__device__ __forceinline__ void gload_lds16(const void* g, void* l) {
    __builtin_amdgcn_global_load_lds(
        (const __attribute__((address_space(1))) unsigned int*)g,
        (__attribute__((address_space(3))) unsigned int*)l, 16, 0, 0);
}

// wa[0:F] = W @ a1 ; wa[F:2F] = W @ a2  — one wave per row of W, float4 loads
__global__ void wa_kernel(const float* __restrict__ W, const float* __restrict__ a,
                          float* __restrict__ wa, int F) {
    int wave = (int)((blockIdx.x * blockDim.x + threadIdx.x) >> 6);
    int lane = threadIdx.x & 63;
    if (wave >= F) return;
    const float4* wr = reinterpret_cast<const float4*>(W + (size_t)wave * F);
    const float4* a1 = reinterpret_cast<const float4*>(a);
    const float4* a2 = reinterpret_cast<const float4*>(a + F);
    float acc1 = 0.f, acc2 = 0.f;
    int F4 = F >> 2;
    for (int c = lane; c < F4; c += 64) {
        float4 w = wr[c];
        float4 x = a1[c];
        float4 y = a2[c];
        acc1 += w.x * x.x + w.y * x.y + w.z * x.z + w.w * x.w;
        acc2 += w.x * y.x + w.y * y.y + w.z * y.z + w.w * y.w;
    }
    #pragma unroll
    for (int off = 32; off; off >>= 1) {
        acc1 += __shfl_down(acc1, off);
        acc2 += __shfl_down(acc2, off);
    }
    if (lane == 0) { wa[wave] = acc1; wa[F + wave] = acc2; }
}

// Merged dispatch: blocks [0,N) do fused scores+softmax+gather (aggregate),
// blocks [N, N + (F/32)^2) do the W->Wt fp16 transpose.
__global__ __launch_bounds__(256) void mid_kernel(
    const float* __restrict__ feat, const float* __restrict__ embed,
    const int* __restrict__ nidx, const float* __restrict__ wa,
    const float* __restrict__ W, _Float16* __restrict__ agg,
    _Float16* __restrict__ Wt, int F, int N) {
    const int tid = threadIdx.x;

    if ((int)blockIdx.x >= N) {
        // ---- transpose part: Wt[n][k] = (fp16) W[k][n], 32x32 tiles ----
        __shared__ float t[32][33];
        const int tb = blockIdx.x - N;
        const int tpr = F >> 5;                 // tiles per row
        const int bx = (tb % tpr) * 32;         // k base
        const int by = (tb / tpr) * 32;         // n base
        const int x = tid & 31, y = tid >> 5;   // (32,8)
        for (int i = y; i < 32; i += 8)
            t[i][x] = W[(size_t)(bx + i) * F + by + x];
        __syncthreads();
        for (int i = y; i < 32; i += 8)
            Wt[(size_t)(by + i) * F + bx + x] = (_Float16)t[x][i];
        return;
    }

    // ---- aggregate part: one block per output row i ----
    const int i = blockIdx.x;
    const int f = tid * 4;

    int idx[MAXK];
    bool dup[MAXK];
    #pragma unroll
    for (int k = 0; k < MAXK; k++) idx[k] = nidx[i * MAXK + k];
    #pragma unroll
    for (int k = 0; k < MAXK; k++) {
        bool d = false;
        #pragma unroll
        for (int p = 0; p < MAXK; p++)
            if (p < k) d |= (idx[p] == idx[k]);
        dup[k] = d;
    }

    float4 wa1 = *(const float4*)&wa[f];
    float4 wa2 = *(const float4*)&wa[F + f];
    float4 fv  = *(const float4*)&feat[(size_t)i * F + f];
    float a1p = fv.x * wa1.x + fv.y * wa1.y + fv.z * wa1.z + fv.w * wa1.w;

    float4 rv[MAXK];
    float a2p[MAXK];
    #pragma unroll
    for (int k = 0; k < MAXK; k++) {
        rv[k] = *(const float4*)&embed[(size_t)idx[k] * F + f];
        a2p[k] = rv[k].x * wa2.x + rv[k].y * wa2.y + rv[k].z * wa2.z + rv[k].w * wa2.w;
    }

    #pragma unroll
    for (int off = 32; off; off >>= 1) {
        a1p += __shfl_down(a1p, off);
        #pragma unroll
        for (int k = 0; k < MAXK; k++) a2p[k] += __shfl_down(a2p[k], off);
    }
    __shared__ float red[MAXK + 1][4];
    const int w = tid >> 6, l = tid & 63;
    if (l == 0) {
        red[0][w] = a1p;
        #pragma unroll
        for (int k = 0; k < MAXK; k++) red[k + 1][w] = a2p[k];
    }
    __syncthreads();

    float s1 = red[0][0] + red[0][1] + red[0][2] + red[0][3];
    float sc[MAXK];
    float m = -INFINITY;
    #pragma unroll
    for (int k = 0; k < MAXK; k++) {
        float v = s1 + red[k + 1][0] + red[k + 1][1] + red[k + 1][2] + red[k + 1][3];
        v = v > 0.f ? v : ALPHA * v;
        sc[k] = v;
        if (!dup[k]) m = fmaxf(m, v);
    }
    float sum = 0.f;
    #pragma unroll
    for (int k = 0; k < MAXK; k++) {
        sc[k] = dup[k] ? 0.f : expf(sc[k] - m);
        sum += sc[k];
    }
    float inv = 1.0f / sum;

    float4 o = make_float4(0.f, 0.f, 0.f, 0.f);
    #pragma unroll
    for (int k = 0; k < MAXK; k++) {
        float wk = sc[k] * inv;
        o.x += wk * rv[k].x;
        o.y += wk * rv[k].y;
        o.z += wk * rv[k].z;
        o.w += wk * rv[k].w;
    }
    half4 h = { (_Float16)o.x, (_Float16)o.y, (_Float16)o.z, (_Float16)o.w };
    *(half4*)&agg[(size_t)i * F + f] = h;
}

// C[M x N] = A[M x K] @ Bt[N x K]^T  (fp16 in, fp32 out, mfma 16x16x32)
// 64x64 tile, BK=64, 4 waves (2m x 2n quadrants). Triple-buffered LDS with
// depth-2 prefetch + counted vmcnt: at iter t we wait only on loads issued at
// iter t-2 (vmcnt(8) leaves stages t+1,t+2 = 8 loads in flight). STAGE for
// t+2 targets buffer (t+2)%3, last read at iter t-1 and protected by the
// end-of-iter barrier. Rule-21 swizzle unchanged:
//   LDS[row][slot] = SRC[row][slot ^ (row&7)]   (slot = 16B granule, 8/row)
__global__ __launch_bounds__(256) void gemm_f16_kernel(
    const _Float16* __restrict__ A, const _Float16* __restrict__ Bt,
    float* __restrict__ C, int M, int N, int K) {
    __shared__ _Float16 As[3][64 * 64];
    __shared__ _Float16 Bs[3][64 * 64];
    const int tid = threadIdx.x;

    int bid = blockIdx.y * gridDim.x + blockIdx.x;
    int nwg = gridDim.x * gridDim.y;
    int cpx = nwg >> 3;                       // nwg % 8 == 0
    int wg = (bid & 7) * cpx + (bid >> 3);
    const int m0 = (wg / gridDim.x) * 64;
    const int n0 = (wg % gridDim.x) * 64;

    const int l = tid & 63, wv = tid >> 6;
    const int wm = wv >> 1, wn = wv & 1;
    const int lrow = l & 15, kc = l >> 4;

    const int srow = l >> 3;                  // 0..7 within row-group
    const int sslot = (l & 7) ^ (srow & 7);   // inverse-swizzled src granule
    const int nt = K >> 6;

    f32x4 acc[2][2] = {};

    const int rg0 = wv * 2, rg1 = wv * 2 + 1;

    #define STAGE(bf, t)                                                           \
    do {                                                                           \
        int k0_ = (t) * 64;                                                        \
        gload_lds16(&A[(size_t)(m0 + rg0 * 8 + srow) * K + k0_ + sslot * 8],       \
                    (void*)((char*)&As[bf][0] + rg0 * 1024 + l * 16));             \
        gload_lds16(&A[(size_t)(m0 + rg1 * 8 + srow) * K + k0_ + sslot * 8],       \
                    (void*)((char*)&As[bf][0] + rg1 * 1024 + l * 16));             \
        gload_lds16(&Bt[(size_t)(n0 + rg0 * 8 + srow) * K + k0_ + sslot * 8],      \
                    (void*)((char*)&Bs[bf][0] + rg0 * 1024 + l * 16));             \
        gload_lds16(&Bt[(size_t)(n0 + rg1 * 8 + srow) * K + k0_ + sslot * 8],      \
                    (void*)((char*)&Bs[bf][0] + rg1 * 1024 + l * 16));             \
    } while (0)

    STAGE(0, 0);
    STAGE(1, 1);

    for (int t = 0; t < nt; ++t) {
        const int buf = t % 3;
        if (t + 2 < nt) STAGE((t + 2) % 3, t + 2);

        if (t + 2 < nt)      asm volatile("s_waitcnt vmcnt(8)" ::: "memory");
        else if (t + 1 < nt) asm volatile("s_waitcnt vmcnt(4)" ::: "memory");
        else                 asm volatile("s_waitcnt vmcnt(0)" ::: "memory");
        __syncthreads();

        half8 av[2][2], bv[2][2];   // [ks][frag]
        #pragma unroll
        for (int ks = 0; ks < 2; ks++) {
            #pragma unroll
            for (int fq = 0; fq < 2; fq++) {
                int arow = wm * 32 + fq * 16 + lrow;
                int aslot = (ks * 4 + kc) ^ (arow & 7);
                av[ks][fq] = *(const half8*)((const char*)&As[buf][0] + arow * 128 + aslot * 16);
                int brow = wn * 32 + fq * 16 + lrow;
                int bslot = (ks * 4 + kc) ^ (brow & 7);
                bv[ks][fq] = *(const half8*)((const char*)&Bs[buf][0] + brow * 128 + bslot * 16);
            }
        }
        #pragma unroll
        for (int ks = 0; ks < 2; ks++)
            #pragma unroll
            for (int fq = 0; fq < 2; fq++)
                #pragma unroll
                for (int g = 0; g < 2; g++)
                    acc[fq][g] = __builtin_amdgcn_mfma_f32_16x16x32_f16(
                        av[ks][fq], bv[ks][g], acc[fq][g], 0, 0, 0);

        __syncthreads();
    }
    #undef STAGE

    // C/D layout: col = lane&15 (=lrow), row = (lane>>4)*4 + r (=kc*4+r)
    #pragma unroll
    for (int fq = 0; fq < 2; fq++)
        #pragma unroll
        for (int g = 0; g < 2; g++)
            #pragma unroll
            for (int r = 0; r < 4; r++)
                C[(size_t)(m0 + wm * 32 + fq * 16 + kc * 4 + r) * N
                  + n0 + wn * 32 + g * 16 + lrow] = acc[fq][g][r];
}

extern "C" void kernel_launch(void* const* d_in, const int* in_sizes, int n_in,
                              void* d_out, int out_size, void* d_ws, size_t ws_size,
                              hipStream_t stream) {
    const float* feat  = (const float*)d_in[0];
    const float* embed = (const float*)d_in[1];
    const float* W     = (const float*)d_in[2];
    const float* a     = (const float*)d_in[3];
    const int*   nidx  = (const int*)d_in[4];

    int F = in_sizes[3] / 2;          // 1024
    int N = in_sizes[0] / F;          // 2048
    int M = in_sizes[1] / F;          // 8192

    float* ws = (float*)d_ws;
    float* wa = ws;                                 // 2F floats
    _Float16* agg_f16 = (_Float16*)(wa + 2 * F);    // N*F halfs
    _Float16* wt_f16  = agg_f16 + (size_t)N * F;    // F*F halfs
    (void)M;

    // wa = W @ [a1, a2]
    wa_kernel<<<(F * 64 + 255) / 256, 256, 0, stream>>>(W, a, wa, F);
    // merged: aggregate (blocks [0,N)) + W->Wt transpose (blocks [N, N+1024))
    {
        int tblocks = (F / 32) * (F / 32);
        mid_kernel<<<N + tblocks, 256, 0, stream>>>(feat, embed, nidx, wa, W,
                                                    agg_f16, wt_f16, F, N);
    }
    // out = agg @ W via MFMA (A=[N][F] fp16, Bt=[F][F] fp16 = W^T)
    {
        dim3 grid(F / 64, N / 64);   // (16, 32) = 512 blocks
        gemm_f16_kernel<<<grid, 256, 0, stream>>>(agg_f16, wt_f16, (float*)d_out, N, F, F);
    }
}

// Round 8
// 38.848 us; speedup vs baseline: 1.0196x; 1.0196x over previous
//
#include <hip/hip_runtime.h>
#include <math.h>

#define ALPHA 0.2f
#define MAXK 10

typedef _Float16 half8 __attribute__((ext_vector_type(8)));
typedef _Float16 half4 __attribute__((ext_vector_type(4)));
typedef float f32x4 __attribute__((ext_vector_type(4)));

__device__ __forceinline__ void gload_lds16(const void* g, void* l) {
    __builtin_amdgcn_global_load_lds(
        (const __attribute__((address_space(1))) unsigned int*)g,
        (__attribute__((address_space(3))) unsigned int*)l, 16, 0, 0);
}

// wa[0:F] = W @ a1 ; wa[F:2F] = W @ a2  — one wave per row of W, float4 loads
__global__ void wa_kernel(const float* __restrict__ W, const float* __restrict__ a,
                          float* __restrict__ wa, int F) {
    int wave = (int)((blockIdx.x * blockDim.x + threadIdx.x) >> 6);
    int lane = threadIdx.x & 63;
    if (wave >= F) return;
    const float4* wr = reinterpret_cast<const float4*>(W + (size_t)wave * F);
    const float4* a1 = reinterpret_cast<const float4*>(a);
    const float4* a2 = reinterpret_cast<const float4*>(a + F);
    float acc1 = 0.f, acc2 = 0.f;
    int F4 = F >> 2;
    for (int c = lane; c < F4; c += 64) {
        float4 w = wr[c];
        float4 x = a1[c];
        float4 y = a2[c];
        acc1 += w.x * x.x + w.y * x.y + w.z * x.z + w.w * x.w;
        acc2 += w.x * y.x + w.y * y.y + w.z * y.z + w.w * y.w;
    }
    #pragma unroll
    for (int off = 32; off; off >>= 1) {
        acc1 += __shfl_down(acc1, off);
        acc2 += __shfl_down(acc2, off);
    }
    if (lane == 0) { wa[wave] = acc1; wa[F + wave] = acc2; }
}

// Merged dispatch: blocks [0,N) do fused scores+softmax+gather (aggregate),
// blocks [N, N + (F/32)^2) do the W->Wt fp16 transpose.
__global__ __launch_bounds__(256) void mid_kernel(
    const float* __restrict__ feat, const float* __restrict__ embed,
    const int* __restrict__ nidx, const float* __restrict__ wa,
    const float* __restrict__ W, _Float16* __restrict__ agg,
    _Float16* __restrict__ Wt, int F, int N) {
    const int tid = threadIdx.x;

    if ((int)blockIdx.x >= N) {
        // ---- transpose part: Wt[n][k] = (fp16) W[k][n], 32x32 tiles ----
        __shared__ float t[32][33];
        const int tb = blockIdx.x - N;
        const int tpr = F >> 5;                 // tiles per row
        const int bx = (tb % tpr) * 32;         // k base
        const int by = (tb / tpr) * 32;         // n base
        const int x = tid & 31, y = tid >> 5;   // (32,8)
        for (int i = y; i < 32; i += 8)
            t[i][x] = W[(size_t)(bx + i) * F + by + x];
        __syncthreads();
        for (int i = y; i < 32; i += 8)
            Wt[(size_t)(by + i) * F + bx + x] = (_Float16)t[x][i];
        return;
    }

    // ---- aggregate part: one block per output row i ----
    const int i = blockIdx.x;
    const int f = tid * 4;

    int idx[MAXK];
    bool dup[MAXK];
    #pragma unroll
    for (int k = 0; k < MAXK; k++) idx[k] = nidx[i * MAXK + k];
    #pragma unroll
    for (int k = 0; k < MAXK; k++) {
        bool d = false;
        #pragma unroll
        for (int p = 0; p < MAXK; p++)
            if (p < k) d |= (idx[p] == idx[k]);
        dup[k] = d;
    }

    float4 wa1 = *(const float4*)&wa[f];
    float4 wa2 = *(const float4*)&wa[F + f];
    float4 fv  = *(const float4*)&feat[(size_t)i * F + f];
    float a1p = fv.x * wa1.x + fv.y * wa1.y + fv.z * wa1.z + fv.w * wa1.w;

    float4 rv[MAXK];
    float a2p[MAXK];
    #pragma unroll
    for (int k = 0; k < MAXK; k++) {
        rv[k] = *(const float4*)&embed[(size_t)idx[k] * F + f];
        a2p[k] = rv[k].x * wa2.x + rv[k].y * wa2.y + rv[k].z * wa2.z + rv[k].w * wa2.w;
    }

    #pragma unroll
    for (int off = 32; off; off >>= 1) {
        a1p += __shfl_down(a1p, off);
        #pragma unroll
        for (int k = 0; k < MAXK; k++) a2p[k] += __shfl_down(a2p[k], off);
    }
    __shared__ float red[MAXK + 1][4];
    const int w = tid >> 6, l = tid & 63;
    if (l == 0) {
        red[0][w] = a1p;
        #pragma unroll
        for (int k = 0; k < MAXK; k++) red[k + 1][w] = a2p[k];
    }
    __syncthreads();

    float s1 = red[0][0] + red[0][1] + red[0][2] + red[0][3];
    float sc[MAXK];
    float m = -INFINITY;
    #pragma unroll
    for (int k = 0; k < MAXK; k++) {
        float v = s1 + red[k + 1][0] + red[k + 1][1] + red[k + 1][2] + red[k + 1][3];
        v = v > 0.f ? v : ALPHA * v;
        sc[k] = v;
        if (!dup[k]) m = fmaxf(m, v);
    }
    float sum = 0.f;
    #pragma unroll
    for (int k = 0; k < MAXK; k++) {
        sc[k] = dup[k] ? 0.f : expf(sc[k] - m);
        sum += sc[k];
    }
    float inv = 1.0f / sum;

    float4 o = make_float4(0.f, 0.f, 0.f, 0.f);
    #pragma unroll
    for (int k = 0; k < MAXK; k++) {
        float wk = sc[k] * inv;
        o.x += wk * rv[k].x;
        o.y += wk * rv[k].y;
        o.z += wk * rv[k].z;
        o.w += wk * rv[k].w;
    }
    half4 h = { (_Float16)o.x, (_Float16)o.y, (_Float16)o.z, (_Float16)o.w };
    *(half4*)&agg[(size_t)i * F + f] = h;
}

// C[M x N] = A[M x K] @ Bt[N x K]^T  (fp16 in, fp32 out, mfma 16x16x32)
// 64x64 tile, BK=64, 4 waves (2m x 2n quadrants). Triple-buffered LDS,
// depth-2 prefetch, counted vmcnt + RAW s_barrier (no __syncthreads drain!).
// Safety: (a) vmcnt(8) before open-barrier => this wave's buffer-t loads
// landed; barrier => all waves'. (b) every ds_read is consumed by an MFMA
// before the close-barrier (compiler lgkmcnt-before-use), so STAGE into that
// buffer next iter is race-free. Rule-21 swizzle:
//   LDS[row][slot] = SRC[row][slot ^ (row&7)]   (slot = 16B granule, 8/row)
__global__ __launch_bounds__(256) void gemm_f16_kernel(
    const _Float16* __restrict__ A, const _Float16* __restrict__ Bt,
    float* __restrict__ C, int M, int N, int K) {
    __shared__ _Float16 As[3][64 * 64];
    __shared__ _Float16 Bs[3][64 * 64];
    const int tid = threadIdx.x;

    int bid = blockIdx.y * gridDim.x + blockIdx.x;
    int nwg = gridDim.x * gridDim.y;
    int cpx = nwg >> 3;                       // nwg % 8 == 0
    int wg = (bid & 7) * cpx + (bid >> 3);
    const int m0 = (wg / gridDim.x) * 64;
    const int n0 = (wg % gridDim.x) * 64;

    const int l = tid & 63, wv = tid >> 6;
    const int wm = wv >> 1, wn = wv & 1;
    const int lrow = l & 15, kc = l >> 4;

    const int srow = l >> 3;                  // 0..7 within row-group
    const int sslot = (l & 7) ^ (srow & 7);   // inverse-swizzled src granule
    const int nt = K >> 6;

    f32x4 acc[2][2] = {};

    const int rg0 = wv * 2, rg1 = wv * 2 + 1;

    #define STAGE(bf, t)                                                           \
    do {                                                                           \
        int k0_ = (t) * 64;                                                        \
        gload_lds16(&A[(size_t)(m0 + rg0 * 8 + srow) * K + k0_ + sslot * 8],       \
                    (void*)((char*)&As[bf][0] + rg0 * 1024 + l * 16));             \
        gload_lds16(&A[(size_t)(m0 + rg1 * 8 + srow) * K + k0_ + sslot * 8],       \
                    (void*)((char*)&As[bf][0] + rg1 * 1024 + l * 16));             \
        gload_lds16(&Bt[(size_t)(n0 + rg0 * 8 + srow) * K + k0_ + sslot * 8],      \
                    (void*)((char*)&Bs[bf][0] + rg0 * 1024 + l * 16));             \
        gload_lds16(&Bt[(size_t)(n0 + rg1 * 8 + srow) * K + k0_ + sslot * 8],      \
                    (void*)((char*)&Bs[bf][0] + rg1 * 1024 + l * 16));             \
    } while (0)

    STAGE(0, 0);
    STAGE(1, 1);

    for (int t = 0; t < nt; ++t) {
        const int buf = t % 3;
        if (t + 2 < nt) STAGE((t + 2) % 3, t + 2);

        if (t + 2 < nt)      asm volatile("s_waitcnt vmcnt(8)" ::: "memory");
        else if (t + 1 < nt) asm volatile("s_waitcnt vmcnt(4)" ::: "memory");
        else                 asm volatile("s_waitcnt vmcnt(0)" ::: "memory");
        __builtin_amdgcn_s_barrier();          // raw: no implicit vmcnt(0) drain
        __builtin_amdgcn_sched_barrier(0);     // pin frag reads behind barrier

        half8 av[2][2], bv[2][2];   // [ks][frag]
        #pragma unroll
        for (int ks = 0; ks < 2; ks++) {
            #pragma unroll
            for (int fq = 0; fq < 2; fq++) {
                int arow = wm * 32 + fq * 16 + lrow;
                int aslot = (ks * 4 + kc) ^ (arow & 7);
                av[ks][fq] = *(const half8*)((const char*)&As[buf][0] + arow * 128 + aslot * 16);
                int brow = wn * 32 + fq * 16 + lrow;
                int bslot = (ks * 4 + kc) ^ (brow & 7);
                bv[ks][fq] = *(const half8*)((const char*)&Bs[buf][0] + brow * 128 + bslot * 16);
            }
        }
        #pragma unroll
        for (int ks = 0; ks < 2; ks++)
            #pragma unroll
            for (int fq = 0; fq < 2; fq++)
                #pragma unroll
                for (int g = 0; g < 2; g++)
                    acc[fq][g] = __builtin_amdgcn_mfma_f32_16x16x32_f16(
                        av[ks][fq], bv[ks][g], acc[fq][g], 0, 0, 0);

        __builtin_amdgcn_sched_barrier(0);     // keep MFMAs (ds_read uses) before close
        __builtin_amdgcn_s_barrier();
    }
    #undef STAGE

    // C/D layout: col = lane&15 (=lrow), row = (lane>>4)*4 + r (=kc*4+r)
    #pragma unroll
    for (int fq = 0; fq < 2; fq++)
        #pragma unroll
        for (int g = 0; g < 2; g++)
            #pragma unroll
            for (int r = 0; r < 4; r++)
                C[(size_t)(m0 + wm * 32 + fq * 16 + kc * 4 + r) * N
                  + n0 + wn * 32 + g * 16 + lrow] = acc[fq][g][r];
}

extern "C" void kernel_launch(void* const* d_in, const int* in_sizes, int n_in,
                              void* d_out, int out_size, void* d_ws, size_t ws_size,
                              hipStream_t stream) {
    const float* feat  = (const float*)d_in[0];
    const float* embed = (const float*)d_in[1];
    const float* W     = (const float*)d_in[2];
    const float* a     = (const float*)d_in[3];
    const int*   nidx  = (const int*)d_in[4];

    int F = in_sizes[3] / 2;          // 1024
    int N = in_sizes[0] / F;          // 2048
    int M = in_sizes[1] / F;          // 8192

    float* ws = (float*)d_ws;
    float* wa = ws;                                 // 2F floats
    _Float16* agg_f16 = (_Float16*)(wa + 2 * F);    // N*F halfs
    _Float16* wt_f16  = agg_f16 + (size_t)N * F;    // F*F halfs
    (void)M;

    // wa = W @ [a1, a2]
    wa_kernel<<<(F * 64 + 255) / 256, 256, 0, stream>>>(W, a, wa, F);
    // merged: aggregate (blocks [0,N)) + W->Wt transpose (blocks [N, N+1024))
    {
        int tblocks = (F / 32) * (F / 32);
        mid_kernel<<<N + tblocks, 256, 0, stream>>>(feat, embed, nidx, wa, W,
                                                    agg_f16, wt_f16, F, N);
    }
    // out = agg @ W via MFMA (A=[N][F] fp16, Bt=[F][F] fp16 = W^T)
    {
        dim3 grid(F / 64, N / 64);   // (16, 32) = 512 blocks
        gemm_f16_kernel<<<grid, 256, 0, stream>>>(agg_f16, wt_f16, (float*)d_out, N, F, F);
    }
}

// Round 9
// 36.789 us; speedup vs baseline: 1.0767x; 1.0560x over previous
//
#include <hip/hip_runtime.h>
#include <math.h>

#define ALPHA 0.2f
#define MAXK 10

typedef _Float16 half8 __attribute__((ext_vector_type(8)));
typedef _Float16 half4 __attribute__((ext_vector_type(4)));
typedef float f32x4 __attribute__((ext_vector_type(4)));

__device__ __forceinline__ void gload_lds16(const void* g, void* l) {
    __builtin_amdgcn_global_load_lds(
        (const __attribute__((address_space(1))) unsigned int*)g,
        (__attribute__((address_space(3))) unsigned int*)l, 16, 0, 0);
}

// wa[0:F] = W @ a1 ; wa[F:2F] = W @ a2  — one wave per row of W, float4 loads
__global__ void wa_kernel(const float* __restrict__ W, const float* __restrict__ a,
                          float* __restrict__ wa, int F) {
    int wave = (int)((blockIdx.x * blockDim.x + threadIdx.x) >> 6);
    int lane = threadIdx.x & 63;
    if (wave >= F) return;
    const float4* wr = reinterpret_cast<const float4*>(W + (size_t)wave * F);
    const float4* a1 = reinterpret_cast<const float4*>(a);
    const float4* a2 = reinterpret_cast<const float4*>(a + F);
    float acc1 = 0.f, acc2 = 0.f;
    int F4 = F >> 2;
    for (int c = lane; c < F4; c += 64) {
        float4 w = wr[c];
        float4 x = a1[c];
        float4 y = a2[c];
        acc1 += w.x * x.x + w.y * x.y + w.z * x.z + w.w * x.w;
        acc2 += w.x * y.x + w.y * y.y + w.z * y.z + w.w * y.w;
    }
    #pragma unroll
    for (int off = 32; off; off >>= 1) {
        acc1 += __shfl_down(acc1, off);
        acc2 += __shfl_down(acc2, off);
    }
    if (lane == 0) { wa[wave] = acc1; wa[F + wave] = acc2; }
}

// Merged dispatch: blocks [0,N) do fused scores+softmax+gather (aggregate),
// blocks [N, N + (F/32)^2) do the W->Wt fp16 transpose.
__global__ __launch_bounds__(256) void mid_kernel(
    const float* __restrict__ feat, const float* __restrict__ embed,
    const int* __restrict__ nidx, const float* __restrict__ wa,
    const float* __restrict__ W, _Float16* __restrict__ agg,
    _Float16* __restrict__ Wt, int F, int N) {
    const int tid = threadIdx.x;

    if ((int)blockIdx.x >= N) {
        // ---- transpose part: Wt[n][k] = (fp16) W[k][n], 32x32 tiles ----
        __shared__ float t[32][33];
        const int tb = blockIdx.x - N;
        const int tpr = F >> 5;                 // tiles per row
        const int bx = (tb % tpr) * 32;         // k base
        const int by = (tb / tpr) * 32;         // n base
        const int x = tid & 31, y = tid >> 5;   // (32,8)
        for (int i = y; i < 32; i += 8)
            t[i][x] = W[(size_t)(bx + i) * F + by + x];
        __syncthreads();
        for (int i = y; i < 32; i += 8)
            Wt[(size_t)(by + i) * F + bx + x] = (_Float16)t[x][i];
        return;
    }

    // ---- aggregate part: one block per output row i ----
    const int i = blockIdx.x;
    const int f = tid * 4;

    int idx[MAXK];
    bool dup[MAXK];
    #pragma unroll
    for (int k = 0; k < MAXK; k++) idx[k] = nidx[i * MAXK + k];
    #pragma unroll
    for (int k = 0; k < MAXK; k++) {
        bool d = false;
        #pragma unroll
        for (int p = 0; p < MAXK; p++)
            if (p < k) d |= (idx[p] == idx[k]);
        dup[k] = d;
    }

    float4 wa1 = *(const float4*)&wa[f];
    float4 wa2 = *(const float4*)&wa[F + f];
    float4 fv  = *(const float4*)&feat[(size_t)i * F + f];
    float a1p = fv.x * wa1.x + fv.y * wa1.y + fv.z * wa1.z + fv.w * wa1.w;

    float4 rv[MAXK];
    float a2p[MAXK];
    #pragma unroll
    for (int k = 0; k < MAXK; k++) {
        rv[k] = *(const float4*)&embed[(size_t)idx[k] * F + f];
        a2p[k] = rv[k].x * wa2.x + rv[k].y * wa2.y + rv[k].z * wa2.z + rv[k].w * wa2.w;
    }

    #pragma unroll
    for (int off = 32; off; off >>= 1) {
        a1p += __shfl_down(a1p, off);
        #pragma unroll
        for (int k = 0; k < MAXK; k++) a2p[k] += __shfl_down(a2p[k], off);
    }
    __shared__ float red[MAXK + 1][4];
    const int w = tid >> 6, l = tid & 63;
    if (l == 0) {
        red[0][w] = a1p;
        #pragma unroll
        for (int k = 0; k < MAXK; k++) red[k + 1][w] = a2p[k];
    }
    __syncthreads();

    float s1 = red[0][0] + red[0][1] + red[0][2] + red[0][3];
    float sc[MAXK];
    float m = -INFINITY;
    #pragma unroll
    for (int k = 0; k < MAXK; k++) {
        float v = s1 + red[k + 1][0] + red[k + 1][1] + red[k + 1][2] + red[k + 1][3];
        v = v > 0.f ? v : ALPHA * v;
        sc[k] = v;
        if (!dup[k]) m = fmaxf(m, v);
    }
    float sum = 0.f;
    #pragma unroll
    for (int k = 0; k < MAXK; k++) {
        sc[k] = dup[k] ? 0.f : expf(sc[k] - m);
        sum += sc[k];
    }
    float inv = 1.0f / sum;

    float4 o = make_float4(0.f, 0.f, 0.f, 0.f);
    #pragma unroll
    for (int k = 0; k < MAXK; k++) {
        float wk = sc[k] * inv;
        o.x += wk * rv[k].x;
        o.y += wk * rv[k].y;
        o.z += wk * rv[k].z;
        o.w += wk * rv[k].w;
    }
    half4 h = { (_Float16)o.x, (_Float16)o.y, (_Float16)o.z, (_Float16)o.w };
    *(half4*)&agg[(size_t)i * F + f] = h;
}

// C[M x N] = A[M x K] @ Bt[N x K]^T  (fp16 in, fp32 out, mfma 16x16x32)
// 64x64 tile, BK=128 (8 iters), 4 waves (2m x 2n quadrants), 2-buffer LDS,
// counted vmcnt(8) + raw s_barrier: the next stage's 8 loads stay in flight
// across the whole ~350cy compute phase. Per-wave order (STAGE -> vmcnt(8)
// -> barrier) guarantees ALL waves' stage-t loads landed once the barrier
// opens. Buffer overwrite safe: close-barrier follows the MFMAs that consume
// the ds_reads (compiler lgkmcnt). Rule-21 swizzle, 16 granules/row:
//   LDS[row][slot] = SRC[row][slot ^ (row&7)]   (slot = 16B granule)
__global__ __launch_bounds__(256) void gemm_f16_kernel(
    const _Float16* __restrict__ A, const _Float16* __restrict__ Bt,
    float* __restrict__ C, int M, int N, int K) {
    __shared__ _Float16 As[2][64 * 128];   // 16KB each
    __shared__ _Float16 Bs[2][64 * 128];
    const int tid = threadIdx.x;

    int bid = blockIdx.y * gridDim.x + blockIdx.x;
    int nwg = gridDim.x * gridDim.y;
    int cpx = nwg >> 3;                       // nwg % 8 == 0
    int wg = (bid & 7) * cpx + (bid >> 3);
    const int m0 = (wg / gridDim.x) * 64;
    const int n0 = (wg % gridDim.x) * 64;

    const int l = tid & 63, wv = tid >> 6;
    const int wm = wv >> 1, wn = wv & 1;
    const int lrow = l & 15, kc = l >> 4;
    const int nt = K >> 7;                    // 8

    f32x4 acc[2][2] = {};

    // staging: per buffer, per wave: 4 A-loads + 4 B-loads (1KB each).
    // load j covers granules u = wv*256 + j*64 + l; row = u>>4, slot = u&15.
    #define STAGE(bf, t)                                                            \
    do {                                                                            \
        int k0_ = (t) * 128;                                                        \
        _Pragma("unroll")                                                           \
        for (int j_ = 0; j_ < 4; j_++) {                                            \
            int u_ = wv * 256 + j_ * 64 + l;                                        \
            int row_ = u_ >> 4, slot_ = (u_ & 15) ^ (row_ & 7);                     \
            gload_lds16(&A[(size_t)(m0 + row_) * K + k0_ + slot_ * 8],              \
                        (void*)((char*)&As[bf][0] + u_ * 16));                      \
        }                                                                           \
        _Pragma("unroll")                                                           \
        for (int j_ = 0; j_ < 4; j_++) {                                            \
            int u_ = wv * 256 + j_ * 64 + l;                                        \
            int row_ = u_ >> 4, slot_ = (u_ & 15) ^ (row_ & 7);                     \
            gload_lds16(&Bt[(size_t)(n0 + row_) * K + k0_ + slot_ * 8],             \
                        (void*)((char*)&Bs[bf][0] + u_ * 16));                      \
        }                                                                           \
    } while (0)

    STAGE(0, 0);

    int buf = 0;
    for (int t = 0; t < nt; ++t) {
        if (t + 1 < nt) {
            STAGE(buf ^ 1, t + 1);
            asm volatile("s_waitcnt vmcnt(8)" ::: "memory");   // stage-t landed
        } else {
            asm volatile("s_waitcnt vmcnt(0)" ::: "memory");
        }
        __builtin_amdgcn_s_barrier();          // raw: no vmcnt(0) drain
        __builtin_amdgcn_sched_barrier(0);

        __builtin_amdgcn_s_setprio(1);
        #pragma unroll
        for (int ks = 0; ks < 4; ks++) {       // 4 x K=32 chunks (BK=128)
            half8 av[2], bv[2];
            #pragma unroll
            for (int fq = 0; fq < 2; fq++) {
                int arow = wm * 32 + fq * 16 + lrow;
                int ag = (ks * 4 + kc) ^ (arow & 7);
                av[fq] = *(const half8*)((const char*)&As[buf][0] + arow * 256 + ag * 16);
                int brow = wn * 32 + fq * 16 + lrow;
                int bg = (ks * 4 + kc) ^ (brow & 7);
                bv[fq] = *(const half8*)((const char*)&Bs[buf][0] + brow * 256 + bg * 16);
            }
            #pragma unroll
            for (int fq = 0; fq < 2; fq++)
                #pragma unroll
                for (int g = 0; g < 2; g++)
                    acc[fq][g] = __builtin_amdgcn_mfma_f32_16x16x32_f16(
                        av[fq], bv[g], acc[fq][g], 0, 0, 0);
        }
        __builtin_amdgcn_s_setprio(0);

        __builtin_amdgcn_sched_barrier(0);     // keep consumes before close
        __builtin_amdgcn_s_barrier();
        buf ^= 1;
    }
    #undef STAGE

    // C/D layout: col = lane&15 (=lrow), row = (lane>>4)*4 + r (=kc*4+r)
    #pragma unroll
    for (int fq = 0; fq < 2; fq++)
        #pragma unroll
        for (int g = 0; g < 2; g++)
            #pragma unroll
            for (int r = 0; r < 4; r++)
                C[(size_t)(m0 + wm * 32 + fq * 16 + kc * 4 + r) * N
                  + n0 + wn * 32 + g * 16 + lrow] = acc[fq][g][r];
}

extern "C" void kernel_launch(void* const* d_in, const int* in_sizes, int n_in,
                              void* d_out, int out_size, void* d_ws, size_t ws_size,
                              hipStream_t stream) {
    const float* feat  = (const float*)d_in[0];
    const float* embed = (const float*)d_in[1];
    const float* W     = (const float*)d_in[2];
    const float* a     = (const float*)d_in[3];
    const int*   nidx  = (const int*)d_in[4];

    int F = in_sizes[3] / 2;          // 1024
    int N = in_sizes[0] / F;          // 2048
    int M = in_sizes[1] / F;          // 8192

    float* ws = (float*)d_ws;
    float* wa = ws;                                 // 2F floats
    _Float16* agg_f16 = (_Float16*)(wa + 2 * F);    // N*F halfs
    _Float16* wt_f16  = agg_f16 + (size_t)N * F;    // F*F halfs
    (void)M;

    // wa = W @ [a1, a2]
    wa_kernel<<<(F * 64 + 255) / 256, 256, 0, stream>>>(W, a, wa, F);
    // merged: aggregate (blocks [0,N)) + W->Wt transpose (blocks [N, N+1024))
    {
        int tblocks = (F / 32) * (F / 32);
        mid_kernel<<<N + tblocks, 256, 0, stream>>>(feat, embed, nidx, wa, W,
                                                    agg_f16, wt_f16, F, N);
    }
    // out = agg @ W via MFMA (A=[N][F] fp16, Bt=[F][F] fp16 = W^T)
    {
        dim3 grid(F / 64, N / 64);   // (16, 32) = 512 blocks
        gemm_f16_kernel<<<grid, 256, 0, stream>>>(agg_f16, wt_f16, (float*)d_out, N, F, F);
    }
}